// Round 7
// baseline (666.256 us; speedup 1.0000x reference)
//
#include <hip/hip_runtime.h>
#include <cstdint>
#include <cstddef>

#define D_MODEL 1024
#define D_INNER 2048
#define D_STATE 16
#define SEQ     2048
#define NROWS   4096   // B * SEQ

typedef short short4v __attribute__((ext_vector_type(4)));
typedef short short8v __attribute__((ext_vector_type(8)));
typedef float float4v __attribute__((ext_vector_type(4)));

__device__ __forceinline__ float bf2f(short u) {
  union { unsigned int i; float f; } v;
  v.i = ((unsigned int)(unsigned short)u) << 16;
  return v.f;
}
__device__ __forceinline__ short f2bf(float f) {
  union { float f; unsigned int i; } v; v.f = f;
  unsigned int r = v.i + 0x7FFFu + ((v.i >> 16) & 1u);  // RNE
  return (short)(r >> 16);
}
// dtype-flagged scalar load: f32==1 -> float*, else bf16
__device__ __forceinline__ float lde(const void* p, size_t i, int f32) {
  return f32 ? ((const float*)p)[i] : bf2f(((const short*)p)[i]);
}
__device__ __forceinline__ void async16(short* lds, const short* g) {
  __builtin_amdgcn_global_load_lds(
      (const __attribute__((address_space(1))) unsigned int*)g,
      (__attribute__((address_space(3))) unsigned int*)lds, 16, 0, 0);
}

// -------- dtype probe ----------
__global__ __launch_bounds__(64) void probe_kernel(const unsigned int* __restrict__ xw,
                                                   int* __restrict__ flag) {
  int cnt = 0;
  for (int i = threadIdx.x; i < 1024; i += 64) {
    unsigned e = (xw[i] >> 7) & 0xFFu;
    cnt += (e >= 100u && e <= 150u) ? 1 : 0;
  }
  #pragma unroll
  for (int o = 32; o >= 1; o >>= 1) cnt += __shfl_xor(cnt, o);
  if (threadIdx.x == 0) *flag = (cnt < 614) ? 1 : 0;   // 1 => fp32 inputs
}

// -------- convert the 3 big weights to bf16 (or copy) ----------
#define WIN_N  4194304u   // 4096*1024
#define WDT_N  4194304u   // 2048*2048
#define WOUT_N 2097152u   // 1024*2048
__global__ __launch_bounds__(256) void cvt_kernel(
    const void* __restrict__ Win, const void* __restrict__ Wdt,
    const void* __restrict__ Wout, short* __restrict__ dst,
    const int* __restrict__ flag) {
  const int f32 = *flag;
  const size_t i = ((size_t)blockIdx.x * 256 + threadIdx.x) * 8;
  const void* src; size_t off;
  if (i < WIN_N)              { src = Win;  off = i; }
  else if (i < WIN_N + WDT_N) { src = Wdt;  off = i - WIN_N; }
  else                        { src = Wout; off = i - WIN_N - WDT_N; }
  if (f32) {
    const float* s = (const float*)src + off;
    short8v o;
    #pragma unroll
    for (int j = 0; j < 8; ++j) o[j] = f2bf(s[j]);
    *(short8v*)&dst[i] = o;
  } else {
    *(short8v*)&dst[i] = *(const short8v*)((const short*)src + off);
  }
}

// -------- LayerNorm ----------
__global__ __launch_bounds__(256) void ln_kernel(
    const void* __restrict__ x, const void* __restrict__ w,
    const void* __restrict__ bb, short* __restrict__ xn,
    const int* __restrict__ flag) {
  const int f32 = *flag;
  const int row = blockIdx.x;
  const int tid = threadIdx.x;
  float v0, v1, v2, v3;
  if (f32) {
    float4v xv = ((const float4v*)((const float*)x + (size_t)row * D_MODEL))[tid];
    v0 = xv[0]; v1 = xv[1]; v2 = xv[2]; v3 = xv[3];
  } else {
    short4v xv = *(const short4v*)&((const short*)x)[(size_t)row * D_MODEL + tid * 4];
    v0 = bf2f(xv[0]); v1 = bf2f(xv[1]); v2 = bf2f(xv[2]); v3 = bf2f(xv[3]);
  }
  float s = v0 + v1 + v2 + v3;
  float q = v0*v0 + v1*v1 + v2*v2 + v3*v3;
  #pragma unroll
  for (int off = 32; off >= 1; off >>= 1) {
    s += __shfl_xor(s, off);
    q += __shfl_xor(q, off);
  }
  __shared__ float red[8];
  const int wid = tid >> 6;
  if ((tid & 63) == 0) { red[wid] = s; red[4 + wid] = q; }
  __syncthreads();
  s = red[0] + red[1] + red[2] + red[3];
  q = red[4] + red[5] + red[6] + red[7];
  const float mu = s * (1.f / 1024.f);
  const float var = q * (1.f / 1024.f) - mu * mu;
  const float rstd = rsqrtf(var + 1e-5f);
  short4v ov;
  #pragma unroll
  for (int j = 0; j < 4; ++j) {
    const float vj = (j == 0) ? v0 : (j == 1) ? v1 : (j == 2) ? v2 : v3;
    const float o = (vj - mu) * rstd * lde(w, tid * 4 + j, f32) + lde(bb, tid * 4 + j, f32);
    ov[j] = f2bf(o);
  }
  *(short4v*)&xn[(size_t)row * D_MODEL + tid * 4] = ov;
}

// -------- MFMA GEMM: C[m,n] = sum_k A[m,k]*B[n,k]; A row stride lda, B stride K
// Software-pipelined: double-buffered LDS (distinct objects), raw s_barrier +
// manual s_waitcnt vmcnt(4) so the k+1 stage stays in flight across compute(k).
// MODE 0: bf16 store; MODE 1: softplus(acc+bias[n]) bf16; MODE 2: acc+resid dtype-flagged
template <int MODE>
__global__ __launch_bounds__(256) void gemm_bt(
    const short* __restrict__ A, int lda, const short* __restrict__ B,
    void* __restrict__ Cv, int N, int K, const void* __restrict__ aux,
    const int* __restrict__ flag) {
  __shared__ __align__(16) short As0[128 * 32];
  __shared__ __align__(16) short As1[128 * 32];
  __shared__ __align__(16) short Bs0[128 * 32];
  __shared__ __align__(16) short Bs1[128 * 32];
  const int f32 = *flag;
  const int tid = threadIdx.x;
  const int bm = blockIdx.y << 7;
  const int bn = blockIdx.x << 7;
  const int wid = tid >> 6;
  const int lane = tid & 63;
  const int wm = (wid >> 1) << 6;
  const int wn = (wid & 1) << 6;

  float4v acc[4][4];
  #pragma unroll
  for (int i = 0; i < 4; ++i)
    #pragma unroll
    for (int j = 0; j < 4; ++j) acc[i][j] = (float4v){0.f, 0.f, 0.f, 0.f};

  const int srow = tid >> 2;
  const int scol = (tid & 3) << 3;
  const short* ga = A + (size_t)(bm + srow) * lda + scol;
  const short* gb = B + (size_t)(bn + srow) * K + scol;
  const size_t astep = (size_t)64 * lda;
  const size_t bstep = (size_t)64 * K;

  const int fr = lane & 15;
  const int fq = (lane >> 4) << 3;

#define STAGE(Ad, Bd, kk) do {                       \
    async16(&Ad[tid * 8], ga + (kk));                \
    async16(&Ad[2048 + tid * 8], ga + astep + (kk)); \
    async16(&Bd[tid * 8], gb + (kk));                \
    async16(&Bd[2048 + tid * 8], gb + bstep + (kk)); } while (0)

  auto compute = [&](const short* Asrc, const short* Bsrc) {
    short8v af[4], bfv[4];
    #pragma unroll
    for (int i = 0; i < 4; ++i)
      af[i] = *(const short8v*)&Asrc[(wm + i * 16 + fr) * 32 + fq];
    #pragma unroll
    for (int j = 0; j < 4; ++j)
      bfv[j] = *(const short8v*)&Bsrc[(wn + j * 16 + fr) * 32 + fq];
    #pragma unroll
    for (int i = 0; i < 4; ++i)
      #pragma unroll
      for (int j = 0; j < 4; ++j)
        acc[i][j] = __builtin_amdgcn_mfma_f32_16x16x32_bf16(af[i], bfv[j], acc[i][j], 0, 0, 0);
  };

  const int nk = K >> 5;   // even for all our K
  STAGE(As0, Bs0, 0);
  for (int k2 = 0; k2 < nk; k2 += 2) {
    STAGE(As1, Bs1, (k2 + 1) << 5);
    __builtin_amdgcn_s_waitcnt(0x3FF4);   // vmcnt(4)
    __builtin_amdgcn_s_barrier();
    compute(As0, Bs0);
    __builtin_amdgcn_s_barrier();
    if (k2 + 2 < nk) {
      STAGE(As0, Bs0, (k2 + 2) << 5);
      __builtin_amdgcn_s_waitcnt(0x3FF4);
    } else {
      __builtin_amdgcn_s_waitcnt(0x3FF0); // vmcnt(0)
    }
    __builtin_amdgcn_s_barrier();
    compute(As1, Bs1);
    __builtin_amdgcn_s_barrier();
  }
#undef STAGE

  const int er = (lane >> 4) << 2;
  const int ec = lane & 15;
  #pragma unroll
  for (int i = 0; i < 4; ++i) {
    #pragma unroll
    for (int j = 0; j < 4; ++j) {
      const int gcol = bn + wn + j * 16 + ec;
      #pragma unroll
      for (int r = 0; r < 4; ++r) {
        const int grow = bm + wm + i * 16 + er + r;
        const size_t idx = (size_t)grow * N + gcol;
        float v = acc[i][j][r];
        if (MODE == 1) {
          v += lde(aux, gcol, f32);
          v = (v > 15.f) ? v : log1pf(__expf(v));
          ((short*)Cv)[idx] = f2bf(v);
        } else if (MODE == 2) {
          v += lde(aux, idx, f32);
          if (f32) ((float*)Cv)[idx] = v;
          else     ((short*)Cv)[idx] = f2bf(v);
        } else {
          ((short*)Cv)[idx] = f2bf(v);
        }
      }
    }
  }
}

// -------- fused causal conv(K=4)+SiLU + B/C projection --------
// block = one (b,t) row, 256 threads. Conv: thread computes 8 channels,
// stages row in LDS + writes xcv. Projection: thread = (n = tid&31, kc = tid>>5)
// covers K=256 with 4 independent accumulator chains; shfl+LDS reduce.
__global__ __launch_bounds__(256) void conv_silu_bc(
    const short* __restrict__ xz, const void* __restrict__ cw,
    const void* __restrict__ cb, short* __restrict__ xc,
    const void* __restrict__ WB, const void* __restrict__ WC,
    float* __restrict__ Bm, float* __restrict__ Cm,
    const int* __restrict__ flag) {
  const int f32 = *flag;
  const int row = blockIdx.x;
  const int tid = threadIdx.x;
  const int c0 = tid << 3;
  const int t = row & (SEQ - 1);

  __shared__ short row_s[2048];
  __shared__ float red[4][32];

  // ---- conv + SiLU ----
  {
    float wreg[32], acc[8];
    #pragma unroll
    for (int j = 0; j < 8; ++j) {
      acc[j] = lde(cb, c0 + j, f32);
      #pragma unroll
      for (int k = 0; k < 4; ++k) wreg[j * 4 + k] = lde(cw, (size_t)(c0 + j) * 4 + k, f32);
    }
    #pragma unroll
    for (int k = 0; k < 4; ++k) {
      if (t + k - 3 >= 0) {
        const short8v xv = *(const short8v*)&xz[(size_t)(row + k - 3) * 4096 + c0];
        #pragma unroll
        for (int j = 0; j < 8; ++j) acc[j] += bf2f(xv[j]) * wreg[j * 4 + k];
      }
    }
    short8v ov;
    #pragma unroll
    for (int j = 0; j < 8; ++j) {
      const float a = acc[j];
      ov[j] = f2bf(a / (1.f + __expf(-a)));
    }
    *(short8v*)&xc[(size_t)row * D_INNER + c0] = ov;
    *(short8v*)&row_s[c0] = ov;
  }
  __syncthreads();

  // ---- B/C projection ----
  const int n = tid & 31;
  const int kc = tid >> 5;        // 0..7
  const int k0 = kc << 8;         // K-chunk of 256
  float a0 = 0.f, a1 = 0.f, a2 = 0.f, a3 = 0.f;
  if (f32) {
    const float* w = ((n < 16) ? (const float*)WB + (size_t)n * D_INNER
                               : (const float*)WC + (size_t)(n - 16) * D_INNER) + k0;
    for (int k = 0; k < 256; k += 32) {
      #pragma unroll
      for (int j = 0; j < 4; ++j) {
        const short8v xv = *(const short8v*)&row_s[k0 + k + j * 8];
        const float4v w0 = *(const float4v*)&w[k + j * 8];
        const float4v w1 = *(const float4v*)&w[k + j * 8 + 4];
        float s = bf2f(xv[0]) * w0[0] + bf2f(xv[1]) * w0[1]
                + bf2f(xv[2]) * w0[2] + bf2f(xv[3]) * w0[3]
                + bf2f(xv[4]) * w1[0] + bf2f(xv[5]) * w1[1]
                + bf2f(xv[6]) * w1[2] + bf2f(xv[7]) * w1[3];
        if (j == 0) a0 += s; else if (j == 1) a1 += s; else if (j == 2) a2 += s; else a3 += s;
      }
    }
  } else {
    const short* w = ((n < 16) ? (const short*)WB + (size_t)n * D_INNER
                               : (const short*)WC + (size_t)(n - 16) * D_INNER) + k0;
    for (int k = 0; k < 256; k += 32) {
      #pragma unroll
      for (int j = 0; j < 4; ++j) {
        const short8v xv = *(const short8v*)&row_s[k0 + k + j * 8];
        const short8v wv = *(const short8v*)&w[k + j * 8];
        float s = bf2f(xv[0]) * bf2f(wv[0]) + bf2f(xv[1]) * bf2f(wv[1])
                + bf2f(xv[2]) * bf2f(wv[2]) + bf2f(xv[3]) * bf2f(wv[3])
                + bf2f(xv[4]) * bf2f(wv[4]) + bf2f(xv[5]) * bf2f(wv[5])
                + bf2f(xv[6]) * bf2f(wv[6]) + bf2f(xv[7]) * bf2f(wv[7]);
        if (j == 0) a0 += s; else if (j == 1) a1 += s; else if (j == 2) a2 += s; else a3 += s;
      }
    }
  }
  float a = (a0 + a1) + (a2 + a3);
  a += __shfl_xor(a, 32);                   // combine kc pair within wave
  const int wid = tid >> 6;
  if ((tid & 63) < 32) red[wid][n] = a;
  __syncthreads();
  if (tid < 32) {
    const float v = red[0][tid] + red[1][tid] + red[2][tid] + red[3][tid];
    if (tid < 16) Bm[(size_t)row * 16 + tid] = v;
    else          Cm[(size_t)row * 16 + (tid - 16)] = v;
  }
}

// -------- chunk-parallel scan, per-thread 16-state, all row-major --------
#define SCAN_CK 64
#define SCAN_ST 32
__global__ __launch_bounds__(1024, 4) void scan_kernel(
    const short* __restrict__ dtb, const short* __restrict__ xcv,
    const float* __restrict__ Bm, const float* __restrict__ Cm,
    short* __restrict__ xzb, const void* __restrict__ A_log,
    const void* __restrict__ Dv, const int* __restrict__ flag) {
  const int f32 = *flag;
  const int tid = threadIdx.x;
  const int dl = tid & 15;
  const int ck = tid >> 4;
  const int di = (blockIdx.x << 4) + dl;
  const int b = blockIdx.y;
  const int r0 = (b << 11) + ck * SCAN_ST;       // global row (b,t0)

  const short* dtp = dtb + (size_t)r0 * 2048 + di;
  const short* xcp = xcv + (size_t)r0 * 2048 + di;
  const float* bmp = Bm + (size_t)r0 * 16;
  const float* cmp = Cm + (size_t)r0 * 16;
  const short* zp = xzb + (size_t)r0 * 4096 + 2048 + di;
  short* yp = xzb + (size_t)r0 * 4096 + di;

  float Ac[16];
  #pragma unroll
  for (int s = 0; s < 16; ++s)
    Ac[s] = -__expf(lde(A_log, (size_t)di * 16 + s, f32));
  const float Dval = lde(Dv, di, f32);

  float h[16];
  #pragma unroll
  for (int s = 0; s < 16; ++s) h[s] = 0.f;
  float sdt = 0.f;

  // pass 1: local scan (h0=0), track sum(dt)
  #pragma unroll 2
  for (int t = 0; t < SCAN_ST; ++t) {
    const float dt = bf2f(dtp[(size_t)t * 2048]);
    const float xc = bf2f(xcp[(size_t)t * 2048]);
    const float4v b0 = *(const float4v*)&bmp[t * 16];
    const float4v b1 = *(const float4v*)&bmp[t * 16 + 4];
    const float4v b2 = *(const float4v*)&bmp[t * 16 + 8];
    const float4v b3 = *(const float4v*)&bmp[t * 16 + 12];
    sdt += dt;
    const float u = xc * dt;
    #pragma unroll
    for (int s = 0; s < 16; ++s) {
      const float bv = (s < 4) ? b0[s] : (s < 8) ? b1[s - 4] : (s < 12) ? b2[s - 8] : b3[s - 12];
      h[s] = h[s] * __expf(Ac[s] * dt) + u * bv;
    }
  }

  __shared__ float sdt_s[SCAN_CK][16];
  __shared__ float hc_s[SCAN_CK][16][17];    // hend in, hstart out (in-place)
  sdt_s[ck][dl] = sdt;
  #pragma unroll
  for (int s = 0; s < 16; ++s) hc_s[ck][dl][s] = h[s];
  __syncthreads();
  if (tid < 256) {
    const int s = tid >> 4;
    const float Acs = -__expf(lde(A_log, (size_t)di * 16 + s, f32));
    float hs = 0.f;
    #pragma unroll 4
    for (int c = 0; c < SCAN_CK; ++c) {
      const float hend = hc_s[c][dl][s];
      hc_s[c][dl][s] = hs;                   // hstart for chunk c
      hs = __expf(Acs * sdt_s[c][dl]) * hs + hend;
    }
  }
  __syncthreads();
  #pragma unroll
  for (int s = 0; s < 16; ++s) h[s] = hc_s[ck][dl][s];

  // pass 2: rescan with true h_start, emit y (coalesced across dl)
  #pragma unroll 2
  for (int t = 0; t < SCAN_ST; ++t) {
    const float dt = bf2f(dtp[(size_t)t * 2048]);
    const float xc = bf2f(xcp[(size_t)t * 2048]);
    const float4v b0 = *(const float4v*)&bmp[t * 16];
    const float4v b1 = *(const float4v*)&bmp[t * 16 + 4];
    const float4v b2 = *(const float4v*)&bmp[t * 16 + 8];
    const float4v b3 = *(const float4v*)&bmp[t * 16 + 12];
    const float4v c0 = *(const float4v*)&cmp[t * 16];
    const float4v c1 = *(const float4v*)&cmp[t * 16 + 4];
    const float4v c2 = *(const float4v*)&cmp[t * 16 + 8];
    const float4v c3 = *(const float4v*)&cmp[t * 16 + 12];
    const float u = xc * dt;
    float p0 = 0.f, p1 = 0.f, p2 = 0.f, p3 = 0.f;
    #pragma unroll
    for (int s = 0; s < 4; ++s) {
      h[s]      = h[s]      * __expf(Ac[s]      * dt) + u * b0[s];
      h[s + 4]  = h[s + 4]  * __expf(Ac[s + 4]  * dt) + u * b1[s];
      h[s + 8]  = h[s + 8]  * __expf(Ac[s + 8]  * dt) + u * b2[s];
      h[s + 12] = h[s + 12] * __expf(Ac[s + 12] * dt) + u * b3[s];
      p0 += h[s] * c0[s];
      p1 += h[s + 4] * c1[s];
      p2 += h[s + 8] * c2[s];
      p3 += h[s + 12] * c3[s];
    }
    const float p = (p0 + p1) + (p2 + p3);
    const float z = bf2f(zp[(size_t)t * 4096]);
    const float sz = z / (1.f + __expf(-z));
    yp[(size_t)t * 4096] = f2bf((p + xc * Dval) * sz);
  }
}

// -------- launch ----------
extern "C" void kernel_launch(void* const* d_in, const int* in_sizes, int n_in,
                              void* d_out, int out_size, void* d_ws, size_t ws_size,
                              hipStream_t stream) {
  const void* x      = d_in[0];
  const void* norm_w = d_in[1];
  const void* norm_b = d_in[2];
  const void* W_in   = d_in[3];
  const void* conv_w = d_in[4];
  const void* conv_b = d_in[5];
  const void* W_dt   = d_in[6];
  const void* b_dt   = d_in[7];
  const void* W_B    = d_in[8];
  const void* W_C    = d_in[9];
  const void* Dv     = d_in[10];
  const void* A_log  = d_in[11];
  const void* W_out  = d_in[12];

  char* ws = (char*)d_ws;
  const size_t MB = (size_t)1 << 20;
  short* wcvt = (short*)(ws);                 //  0-20 MB: W_in | W_dt | W_out (bf16)
  short* wbuf = wcvt;
  short* wdt  = wcvt + WIN_N;
  short* wout = wcvt + WIN_N + WDT_N;
  int*   flag = (int*)(ws + 20 * MB);
  short* xzb  = (short*)(ws + 21 * MB);       // 21-53 MB [4096 x 4096] (z kept; y overwrites x_part)
  short* xcv  = (short*)(ws + 53 * MB);       // 53-69 MB xc row-major
  short* xn   = (short*)(ws + 69 * MB);       //  8 MB (aliased with dtb)
  short* dtb  = (short*)(ws + 69 * MB);       // 69-85 MB dt row-major [(b,t)][di]
  float* Bm   = (float*)(ws + 85 * MB);       // 256 KB [(b,t)][s]
  float* Cm   = Bm + (size_t)NROWS * 16;      // 256 KB

  probe_kernel<<<1, 64, 0, stream>>>((const unsigned int*)x, flag);
  cvt_kernel<<<5120, 256, 0, stream>>>(W_in, W_dt, W_out, wcvt, flag);
  ln_kernel<<<NROWS, 256, 0, stream>>>(x, norm_w, norm_b, xn, flag);
  gemm_bt<0><<<dim3(32, 32), 256, 0, stream>>>(xn, 1024, wbuf, xzb, 4096, 1024, nullptr, flag);
  conv_silu_bc<<<NROWS, 256, 0, stream>>>(xzb, conv_w, conv_b, xcv, W_B, W_C, Bm, Cm, flag);
  gemm_bt<1><<<dim3(16, 32), 256, 0, stream>>>(xcv, 2048, wdt, dtb, 2048, 2048, b_dt, flag);
  scan_kernel<<<dim3(128, 2), 1024, 0, stream>>>(dtb, xcv, Bm, Cm, xzb, A_log, Dv, flag);
  gemm_bt<2><<<dim3(8, 32), 256, 0, stream>>>(xzb, 4096, wout, d_out, 1024, 2048, x, flag);
}

// Round 8
// 551.759 us; speedup vs baseline: 1.2075x; 1.2075x over previous
//
#include <hip/hip_runtime.h>
#include <cstdint>
#include <cstddef>

#define D_MODEL 1024
#define D_INNER 2048
#define D_STATE 16
#define SEQ     2048
#define NROWS   4096   // B * SEQ

typedef short short4v __attribute__((ext_vector_type(4)));
typedef short short8v __attribute__((ext_vector_type(8)));
typedef float float4v __attribute__((ext_vector_type(4)));

__device__ __forceinline__ float bf2f(short u) {
  union { unsigned int i; float f; } v;
  v.i = ((unsigned int)(unsigned short)u) << 16;
  return v.f;
}
__device__ __forceinline__ short f2bf(float f) {
  union { float f; unsigned int i; } v; v.f = f;
  unsigned int r = v.i + 0x7FFFu + ((v.i >> 16) & 1u);  // RNE
  return (short)(r >> 16);
}
// dtype-flagged scalar load: f32==1 -> float*, else bf16
__device__ __forceinline__ float lde(const void* p, size_t i, int f32) {
  return f32 ? ((const float*)p)[i] : bf2f(((const short*)p)[i]);
}
__device__ __forceinline__ void async16(short* lds, const short* g) {
  __builtin_amdgcn_global_load_lds(
      (const __attribute__((address_space(1))) unsigned int*)g,
      (__attribute__((address_space(3))) unsigned int*)lds, 16, 0, 0);
}

// -------- dtype probe ----------
__global__ __launch_bounds__(64) void probe_kernel(const unsigned int* __restrict__ xw,
                                                   int* __restrict__ flag) {
  int cnt = 0;
  for (int i = threadIdx.x; i < 1024; i += 64) {
    unsigned e = (xw[i] >> 7) & 0xFFu;
    cnt += (e >= 100u && e <= 150u) ? 1 : 0;
  }
  #pragma unroll
  for (int o = 32; o >= 1; o >>= 1) cnt += __shfl_xor(cnt, o);
  if (threadIdx.x == 0) *flag = (cnt < 614) ? 1 : 0;   // 1 => fp32 inputs
}

// -------- convert weights to bf16: [W_in | W_dt;W_B;W_C;pad | W_out] ----------
#define WIN_N  4194304u                 // 4096*1024
#define WDT_N  4194304u                 // 2048*2048
#define WBC_N  32768u                   // 16*2048
#define WPAD_N 196608u                  // 96*2048  (zero pad rows 2080..2175)
#define WCAT_N (WDT_N + 2u*WBC_N + WPAD_N)   // 2176*2048 = 4456448
#define WOUT_N 2097152u                 // 1024*2048
#define CVT_TOT (WIN_N + WCAT_N + WOUT_N)    // 10747904 (= 5248*256*8)
__global__ __launch_bounds__(256) void cvt_kernel(
    const void* __restrict__ Win, const void* __restrict__ Wdt,
    const void* __restrict__ WBp, const void* __restrict__ WCp,
    const void* __restrict__ Wout, short* __restrict__ dst,
    const int* __restrict__ flag) {
  const int f32 = *flag;
  const size_t i = ((size_t)blockIdx.x * 256 + threadIdx.x) * 8;
  const void* src = nullptr; size_t off = 0; bool zero = false;
  if (i < WIN_N) { src = Win; off = i; }
  else {
    size_t j = i - WIN_N;
    if (j < WDT_N) { src = Wdt; off = j; }
    else {
      j -= WDT_N;
      if (j < WBC_N) { src = WBp; off = j; }
      else {
        j -= WBC_N;
        if (j < WBC_N) { src = WCp; off = j; }
        else {
          j -= WBC_N;
          if (j < WPAD_N) zero = true;
          else { src = Wout; off = j - WPAD_N; }
        }
      }
    }
  }
  short8v o;
  if (zero) {
    #pragma unroll
    for (int j = 0; j < 8; ++j) o[j] = 0;
  } else if (f32) {
    const float* s = (const float*)src + off;
    #pragma unroll
    for (int j = 0; j < 8; ++j) o[j] = f2bf(s[j]);
  } else {
    o = *(const short8v*)((const short*)src + off);
  }
  *(short8v*)&dst[i] = o;
}

// -------- LayerNorm ----------
__global__ __launch_bounds__(256) void ln_kernel(
    const void* __restrict__ x, const void* __restrict__ w,
    const void* __restrict__ bb, short* __restrict__ xn,
    const int* __restrict__ flag) {
  const int f32 = *flag;
  const int row = blockIdx.x;
  const int tid = threadIdx.x;
  float v0, v1, v2, v3;
  if (f32) {
    float4v xv = ((const float4v*)((const float*)x + (size_t)row * D_MODEL))[tid];
    v0 = xv[0]; v1 = xv[1]; v2 = xv[2]; v3 = xv[3];
  } else {
    short4v xv = *(const short4v*)&((const short*)x)[(size_t)row * D_MODEL + tid * 4];
    v0 = bf2f(xv[0]); v1 = bf2f(xv[1]); v2 = bf2f(xv[2]); v3 = bf2f(xv[3]);
  }
  float s = v0 + v1 + v2 + v3;
  float q = v0*v0 + v1*v1 + v2*v2 + v3*v3;
  #pragma unroll
  for (int off = 32; off >= 1; off >>= 1) {
    s += __shfl_xor(s, off);
    q += __shfl_xor(q, off);
  }
  __shared__ float red[8];
  const int wid = tid >> 6;
  if ((tid & 63) == 0) { red[wid] = s; red[4 + wid] = q; }
  __syncthreads();
  s = red[0] + red[1] + red[2] + red[3];
  q = red[4] + red[5] + red[6] + red[7];
  const float mu = s * (1.f / 1024.f);
  const float var = q * (1.f / 1024.f) - mu * mu;
  const float rstd = rsqrtf(var + 1e-5f);
  short4v ov;
  #pragma unroll
  for (int j = 0; j < 4; ++j) {
    const float vj = (j == 0) ? v0 : (j == 1) ? v1 : (j == 2) ? v2 : v3;
    const float o = (vj - mu) * rstd * lde(w, tid * 4 + j, f32) + lde(bb, tid * 4 + j, f32);
    ov[j] = f2bf(o);
  }
  *(short4v*)&xn[(size_t)row * D_MODEL + tid * 4] = ov;
}

// -------- MFMA GEMM: C[m,n] = sum_k A[m,k]*B[n,k]; A row stride lda, B stride K
// Software-pipelined double-buffered LDS + raw s_barrier + manual vmcnt(4).
// MODE 0: bf16 store row-major (stride N)
// MODE 1: col<2048 -> softplus(acc+bias[col]) bf16 into Cv (stride 2048);
//         2048..2063 -> Bmo fp32 [row][16]; 2064..2079 -> Cmo; >=2080 discard
// MODE 2: acc+resid -> dtype-flagged store (stride N)
template <int MODE>
__global__ __launch_bounds__(256) void gemm_bt(
    const short* __restrict__ A, int lda, const short* __restrict__ B,
    void* __restrict__ Cv, int N, int K, const void* __restrict__ aux,
    float* __restrict__ Bmo, float* __restrict__ Cmo,
    const int* __restrict__ flag) {
  __shared__ __align__(16) short As0[128 * 32];
  __shared__ __align__(16) short As1[128 * 32];
  __shared__ __align__(16) short Bs0[128 * 32];
  __shared__ __align__(16) short Bs1[128 * 32];
  const int f32 = *flag;
  const int tid = threadIdx.x;
  const int bm = blockIdx.y << 7;
  const int bn = blockIdx.x << 7;
  const int wid = tid >> 6;
  const int lane = tid & 63;
  const int wm = (wid >> 1) << 6;
  const int wn = (wid & 1) << 6;

  float4v acc[4][4];
  #pragma unroll
  for (int i = 0; i < 4; ++i)
    #pragma unroll
    for (int j = 0; j < 4; ++j) acc[i][j] = (float4v){0.f, 0.f, 0.f, 0.f};

  const int srow = tid >> 2;
  const int scol = (tid & 3) << 3;
  const short* ga = A + (size_t)(bm + srow) * lda + scol;
  const short* gb = B + (size_t)(bn + srow) * K + scol;
  const size_t astep = (size_t)64 * lda;
  const size_t bstep = (size_t)64 * K;

  const int fr = lane & 15;
  const int fq = (lane >> 4) << 3;

#define STAGE(Ad, Bd, kk) do {                       \
    async16(&Ad[tid * 8], ga + (kk));                \
    async16(&Ad[2048 + tid * 8], ga + astep + (kk)); \
    async16(&Bd[tid * 8], gb + (kk));                \
    async16(&Bd[2048 + tid * 8], gb + bstep + (kk)); } while (0)

  auto compute = [&](const short* Asrc, const short* Bsrc) {
    short8v af[4], bfv[4];
    #pragma unroll
    for (int i = 0; i < 4; ++i)
      af[i] = *(const short8v*)&Asrc[(wm + i * 16 + fr) * 32 + fq];
    #pragma unroll
    for (int j = 0; j < 4; ++j)
      bfv[j] = *(const short8v*)&Bsrc[(wn + j * 16 + fr) * 32 + fq];
    #pragma unroll
    for (int i = 0; i < 4; ++i)
      #pragma unroll
      for (int j = 0; j < 4; ++j)
        acc[i][j] = __builtin_amdgcn_mfma_f32_16x16x32_bf16(af[i], bfv[j], acc[i][j], 0, 0, 0);
  };

  const int nk = K >> 5;   // even for all our K
  STAGE(As0, Bs0, 0);
  for (int k2 = 0; k2 < nk; k2 += 2) {
    STAGE(As1, Bs1, (k2 + 1) << 5);
    __builtin_amdgcn_s_waitcnt(0x3FF4);   // vmcnt(4)
    __builtin_amdgcn_s_barrier();
    compute(As0, Bs0);
    __builtin_amdgcn_s_barrier();
    if (k2 + 2 < nk) {
      STAGE(As0, Bs0, (k2 + 2) << 5);
      __builtin_amdgcn_s_waitcnt(0x3FF4);
    } else {
      __builtin_amdgcn_s_waitcnt(0x3FF0); // vmcnt(0)
    }
    __builtin_amdgcn_s_barrier();
    compute(As1, Bs1);
    __builtin_amdgcn_s_barrier();
  }
#undef STAGE

  const int er = (lane >> 4) << 2;
  const int ec = lane & 15;
  #pragma unroll
  for (int i = 0; i < 4; ++i) {
    #pragma unroll
    for (int j = 0; j < 4; ++j) {
      const int gcol = bn + wn + j * 16 + ec;
      #pragma unroll
      for (int r = 0; r < 4; ++r) {
        const int grow = bm + wm + i * 16 + er + r;
        float v = acc[i][j][r];
        if (MODE == 1) {
          if (gcol < 2048) {
            v += lde(aux, gcol, f32);
            v = (v > 15.f) ? v : log1pf(__expf(v));
            ((short*)Cv)[(size_t)grow * 2048 + gcol] = f2bf(v);
          } else if (gcol < 2064) {
            Bmo[(size_t)grow * 16 + (gcol - 2048)] = v;
          } else if (gcol < 2080) {
            Cmo[(size_t)grow * 16 + (gcol - 2064)] = v;
          }
        } else {
          const size_t idx = (size_t)grow * N + gcol;
          if (MODE == 2) {
            v += lde(aux, idx, f32);
            if (f32) ((float*)Cv)[idx] = v;
            else     ((short*)Cv)[idx] = f2bf(v);
          } else {
            ((short*)Cv)[idx] = f2bf(v);
          }
        }
      }
    }
  }
}

// -------- causal depthwise conv (K=4) + SiLU ----------
__global__ __launch_bounds__(256) void conv_silu(
    const short* __restrict__ xz, const void* __restrict__ cw,
    const void* __restrict__ cb, short* __restrict__ xc,
    const int* __restrict__ flag) {
  const int f32 = *flag;
  const int row = blockIdx.x;
  const int c0 = threadIdx.x << 3;
  const int t = row & (SEQ - 1);
  float wreg[32], acc[8];
  #pragma unroll
  for (int j = 0; j < 8; ++j) {
    acc[j] = lde(cb, c0 + j, f32);
    #pragma unroll
    for (int k = 0; k < 4; ++k) wreg[j * 4 + k] = lde(cw, (size_t)(c0 + j) * 4 + k, f32);
  }
  #pragma unroll
  for (int k = 0; k < 4; ++k) {
    if (t + k - 3 >= 0) {
      const short8v xv = *(const short8v*)&xz[(size_t)(row + k - 3) * 4096 + c0];
      #pragma unroll
      for (int j = 0; j < 8; ++j) acc[j] += bf2f(xv[j]) * wreg[j * 4 + k];
    }
  }
  short8v ov;
  #pragma unroll
  for (int j = 0; j < 8; ++j) {
    const float a = acc[j];
    ov[j] = f2bf(a / (1.f + __expf(-a)));
  }
  *(short8v*)&xc[(size_t)row * D_INNER + c0] = ov;
}

// -------- chunk-parallel scan, per-thread 16-state, all row-major --------
#define SCAN_CK 64
#define SCAN_ST 32
__global__ __launch_bounds__(1024, 4) void scan_kernel(
    const short* __restrict__ dtb, const short* __restrict__ xcv,
    const float* __restrict__ Bm, const float* __restrict__ Cm,
    short* __restrict__ xzb, const void* __restrict__ A_log,
    const void* __restrict__ Dv, const int* __restrict__ flag) {
  const int f32 = *flag;
  const int tid = threadIdx.x;
  const int dl = tid & 15;
  const int ck = tid >> 4;
  const int di = (blockIdx.x << 4) + dl;
  const int b = blockIdx.y;
  const int r0 = (b << 11) + ck * SCAN_ST;       // global row (b,t0)

  const short* dtp = dtb + (size_t)r0 * 2048 + di;
  const short* xcp = xcv + (size_t)r0 * 2048 + di;
  const float* bmp = Bm + (size_t)r0 * 16;
  const float* cmp = Cm + (size_t)r0 * 16;
  const short* zp = xzb + (size_t)r0 * 4096 + 2048 + di;
  short* yp = xzb + (size_t)r0 * 4096 + di;

  float Ac[16];
  #pragma unroll
  for (int s = 0; s < 16; ++s)
    Ac[s] = -__expf(lde(A_log, (size_t)di * 16 + s, f32));
  const float Dval = lde(Dv, di, f32);

  float h[16];
  #pragma unroll
  for (int s = 0; s < 16; ++s) h[s] = 0.f;
  float sdt = 0.f;

  // pass 1: local scan (h0=0), track sum(dt)
  #pragma unroll 2
  for (int t = 0; t < SCAN_ST; ++t) {
    const float dt = bf2f(dtp[(size_t)t * 2048]);
    const float xc = bf2f(xcp[(size_t)t * 2048]);
    const float4v b0 = *(const float4v*)&bmp[t * 16];
    const float4v b1 = *(const float4v*)&bmp[t * 16 + 4];
    const float4v b2 = *(const float4v*)&bmp[t * 16 + 8];
    const float4v b3 = *(const float4v*)&bmp[t * 16 + 12];
    sdt += dt;
    const float u = xc * dt;
    #pragma unroll
    for (int s = 0; s < 16; ++s) {
      const float bv = (s < 4) ? b0[s] : (s < 8) ? b1[s - 4] : (s < 12) ? b2[s - 8] : b3[s - 12];
      h[s] = h[s] * __expf(Ac[s] * dt) + u * bv;
    }
  }

  __shared__ float sdt_s[SCAN_CK][16];
  __shared__ float hc_s[SCAN_CK][16][17];    // hend in, hstart out (in-place)
  sdt_s[ck][dl] = sdt;
  #pragma unroll
  for (int s = 0; s < 16; ++s) hc_s[ck][dl][s] = h[s];
  __syncthreads();
  if (tid < 256) {
    const int s = tid >> 4;
    const float Acs = -__expf(lde(A_log, (size_t)di * 16 + s, f32));
    float hs = 0.f;
    #pragma unroll 4
    for (int c = 0; c < SCAN_CK; ++c) {
      const float hend = hc_s[c][dl][s];
      hc_s[c][dl][s] = hs;                   // hstart for chunk c
      hs = __expf(Acs * sdt_s[c][dl]) * hs + hend;
    }
  }
  __syncthreads();
  #pragma unroll
  for (int s = 0; s < 16; ++s) h[s] = hc_s[ck][dl][s];

  // pass 2: rescan with true h_start, emit y (coalesced across dl)
  #pragma unroll 2
  for (int t = 0; t < SCAN_ST; ++t) {
    const float dt = bf2f(dtp[(size_t)t * 2048]);
    const float xc = bf2f(xcp[(size_t)t * 2048]);
    const float4v b0 = *(const float4v*)&bmp[t * 16];
    const float4v b1 = *(const float4v*)&bmp[t * 16 + 4];
    const float4v b2 = *(const float4v*)&bmp[t * 16 + 8];
    const float4v b3 = *(const float4v*)&bmp[t * 16 + 12];
    const float4v c0 = *(const float4v*)&cmp[t * 16];
    const float4v c1 = *(const float4v*)&cmp[t * 16 + 4];
    const float4v c2 = *(const float4v*)&cmp[t * 16 + 8];
    const float4v c3 = *(const float4v*)&cmp[t * 16 + 12];
    const float u = xc * dt;
    float p0 = 0.f, p1 = 0.f, p2 = 0.f, p3 = 0.f;
    #pragma unroll
    for (int s = 0; s < 4; ++s) {
      h[s]      = h[s]      * __expf(Ac[s]      * dt) + u * b0[s];
      h[s + 4]  = h[s + 4]  * __expf(Ac[s + 4]  * dt) + u * b1[s];
      h[s + 8]  = h[s + 8]  * __expf(Ac[s + 8]  * dt) + u * b2[s];
      h[s + 12] = h[s + 12] * __expf(Ac[s + 12] * dt) + u * b3[s];
      p0 += h[s] * c0[s];
      p1 += h[s + 4] * c1[s];
      p2 += h[s + 8] * c2[s];
      p3 += h[s + 12] * c3[s];
    }
    const float p = (p0 + p1) + (p2 + p3);
    const float z = bf2f(zp[(size_t)t * 4096]);
    const float sz = z / (1.f + __expf(-z));
    yp[(size_t)t * 4096] = f2bf((p + xc * Dval) * sz);
  }
}

// -------- launch ----------
extern "C" void kernel_launch(void* const* d_in, const int* in_sizes, int n_in,
                              void* d_out, int out_size, void* d_ws, size_t ws_size,
                              hipStream_t stream) {
  const void* x      = d_in[0];
  const void* norm_w = d_in[1];
  const void* norm_b = d_in[2];
  const void* W_in   = d_in[3];
  const void* conv_w = d_in[4];
  const void* conv_b = d_in[5];
  const void* W_dt   = d_in[6];
  const void* b_dt   = d_in[7];
  const void* W_B    = d_in[8];
  const void* W_C    = d_in[9];
  const void* Dv     = d_in[10];
  const void* A_log  = d_in[11];
  const void* W_out  = d_in[12];

  char* ws = (char*)d_ws;
  const size_t MB = (size_t)1 << 20;
  short* wcvt = (short*)(ws);                 //  0-20.5 MB: W_in | [W_dt;W_B;W_C;pad] | W_out
  short* wbuf = wcvt;
  short* wcat = wcvt + WIN_N;                 // 2176 x 2048 bf16
  short* wout = wcvt + WIN_N + WCAT_N;
  int*   flag = (int*)(ws + 21 * MB - 256);
  short* xzb  = (short*)(ws + 21 * MB);       // 21-53 MB [4096 x 4096] (z kept; y overwrites x_part)
  short* xcv  = (short*)(ws + 53 * MB);       // 53-69 MB xc row-major
  short* xn   = (short*)(ws + 69 * MB);       //  8 MB (aliased with dtb)
  short* dtb  = (short*)(ws + 69 * MB);       // 69-85 MB dt row-major [(b,t)][di]
  float* Bm   = (float*)(ws + 85 * MB);       // 256 KB [(b,t)][s]
  float* Cm   = Bm + (size_t)NROWS * 16;      // 256 KB

  probe_kernel<<<1, 64, 0, stream>>>((const unsigned int*)x, flag);
  cvt_kernel<<<5248, 256, 0, stream>>>(W_in, W_dt, W_B, W_C, W_out, wcvt, flag);
  ln_kernel<<<NROWS, 256, 0, stream>>>(x, norm_w, norm_b, xn, flag);
  gemm_bt<0><<<dim3(32, 32), 256, 0, stream>>>(xn, 1024, wbuf, xzb, 4096, 1024, nullptr, nullptr, nullptr, flag);
  conv_silu<<<NROWS, 256, 0, stream>>>(xzb, conv_w, conv_b, xcv, flag);
  gemm_bt<1><<<dim3(17, 32), 256, 0, stream>>>(xcv, 2048, wcat, dtb, 2176, 2048, b_dt, Bm, Cm, flag);
  scan_kernel<<<dim3(128, 2), 1024, 0, stream>>>(dtb, xcv, Bm, Cm, xzb, A_log, Dv, flag);
  gemm_bt<2><<<dim3(8, 32), 256, 0, stream>>>(xzb, 4096, wout, d_out, 1024, 2048, x, nullptr, nullptr, flag);
}

// Round 9
// 522.698 us; speedup vs baseline: 1.2746x; 1.0556x over previous
//
#include <hip/hip_runtime.h>
#include <cstdint>
#include <cstddef>

#define D_MODEL 1024
#define D_INNER 2048
#define D_STATE 16
#define SEQ     2048
#define NROWS   4096   // B * SEQ

typedef short short4v __attribute__((ext_vector_type(4)));
typedef short short8v __attribute__((ext_vector_type(8)));
typedef float float4v __attribute__((ext_vector_type(4)));

__device__ __forceinline__ float bf2f(short u) {
  union { unsigned int i; float f; } v;
  v.i = ((unsigned int)(unsigned short)u) << 16;
  return v.f;
}
__device__ __forceinline__ short f2bf(float f) {
  union { float f; unsigned int i; } v; v.f = f;
  unsigned int r = v.i + 0x7FFFu + ((v.i >> 16) & 1u);  // RNE
  return (short)(r >> 16);
}
// dtype-flagged scalar load: f32==1 -> float*, else bf16
__device__ __forceinline__ float lde(const void* p, size_t i, int f32) {
  return f32 ? ((const float*)p)[i] : bf2f(((const short*)p)[i]);
}
__device__ __forceinline__ void async16(short* lds, const short* g) {
  __builtin_amdgcn_global_load_lds(
      (const __attribute__((address_space(1))) unsigned int*)g,
      (__attribute__((address_space(3))) unsigned int*)lds, 16, 0, 0);
}

// -------- dtype probe ----------
__global__ __launch_bounds__(64) void probe_kernel(const unsigned int* __restrict__ xw,
                                                   int* __restrict__ flag) {
  int cnt = 0;
  for (int i = threadIdx.x; i < 1024; i += 64) {
    unsigned e = (xw[i] >> 7) & 0xFFu;
    cnt += (e >= 100u && e <= 150u) ? 1 : 0;
  }
  #pragma unroll
  for (int o = 32; o >= 1; o >>= 1) cnt += __shfl_xor(cnt, o);
  if (threadIdx.x == 0) *flag = (cnt < 614) ? 1 : 0;   // 1 => fp32 inputs
}

// -------- convert weights to bf16: [W_in | W_dt;W_B;W_C;pad | W_out] ----------
#define WIN_N  4194304u                 // 4096*1024
#define WDT_N  4194304u                 // 2048*2048
#define WBC_N  32768u                   // 16*2048
#define WPAD_N 196608u                  // 96*2048  (zero pad rows 2080..2175)
#define WCAT_N (WDT_N + 2u*WBC_N + WPAD_N)   // 2176*2048 = 4456448
#define WOUT_N 2097152u                 // 1024*2048
__global__ __launch_bounds__(256) void cvt_kernel(
    const void* __restrict__ Win, const void* __restrict__ Wdt,
    const void* __restrict__ WBp, const void* __restrict__ WCp,
    const void* __restrict__ Wout, short* __restrict__ dst,
    const int* __restrict__ flag) {
  const int f32 = *flag;
  const size_t i = ((size_t)blockIdx.x * 256 + threadIdx.x) * 8;
  const void* src = nullptr; size_t off = 0; bool zero = false;
  if (i < WIN_N) { src = Win; off = i; }
  else {
    size_t j = i - WIN_N;
    if (j < WDT_N) { src = Wdt; off = j; }
    else {
      j -= WDT_N;
      if (j < WBC_N) { src = WBp; off = j; }
      else {
        j -= WBC_N;
        if (j < WBC_N) { src = WCp; off = j; }
        else {
          j -= WBC_N;
          if (j < WPAD_N) zero = true;
          else { src = Wout; off = j - WPAD_N; }
        }
      }
    }
  }
  short8v o;
  if (zero) {
    #pragma unroll
    for (int j = 0; j < 8; ++j) o[j] = 0;
  } else if (f32) {
    const float* s = (const float*)src + off;
    #pragma unroll
    for (int j = 0; j < 8; ++j) o[j] = f2bf(s[j]);
  } else {
    o = *(const short8v*)((const short*)src + off);
  }
  *(short8v*)&dst[i] = o;
}

// -------- LayerNorm ----------
__global__ __launch_bounds__(256) void ln_kernel(
    const void* __restrict__ x, const void* __restrict__ w,
    const void* __restrict__ bb, short* __restrict__ xn,
    const int* __restrict__ flag) {
  const int f32 = *flag;
  const int row = blockIdx.x;
  const int tid = threadIdx.x;
  float v0, v1, v2, v3;
  if (f32) {
    float4v xv = ((const float4v*)((const float*)x + (size_t)row * D_MODEL))[tid];
    v0 = xv[0]; v1 = xv[1]; v2 = xv[2]; v3 = xv[3];
  } else {
    short4v xv = *(const short4v*)&((const short*)x)[(size_t)row * D_MODEL + tid * 4];
    v0 = bf2f(xv[0]); v1 = bf2f(xv[1]); v2 = bf2f(xv[2]); v3 = bf2f(xv[3]);
  }
  float s = v0 + v1 + v2 + v3;
  float q = v0*v0 + v1*v1 + v2*v2 + v3*v3;
  #pragma unroll
  for (int off = 32; off >= 1; off >>= 1) {
    s += __shfl_xor(s, off);
    q += __shfl_xor(q, off);
  }
  __shared__ float red[8];
  const int wid = tid >> 6;
  if ((tid & 63) == 0) { red[wid] = s; red[4 + wid] = q; }
  __syncthreads();
  s = red[0] + red[1] + red[2] + red[3];
  q = red[4] + red[5] + red[6] + red[7];
  const float mu = s * (1.f / 1024.f);
  const float var = q * (1.f / 1024.f) - mu * mu;
  const float rstd = rsqrtf(var + 1e-5f);
  short4v ov;
  #pragma unroll
  for (int j = 0; j < 4; ++j) {
    const float vj = (j == 0) ? v0 : (j == 1) ? v1 : (j == 2) ? v2 : v3;
    const float o = (vj - mu) * rstd * lde(w, tid * 4 + j, f32) + lde(bb, tid * 4 + j, f32);
    ov[j] = f2bf(o);
  }
  *(short4v*)&xn[(size_t)row * D_MODEL + tid * 4] = ov;
}

// -------- MFMA GEMM: C[m,n] = sum_k A[m,k]*B[n,k]; A row stride lda, B stride K
// Tile BM x 128, block = 2*BM threads (BM/32 waves), double-buffered LDS,
// raw s_barrier + manual vmcnt(stage-DMA-count) pipeline.
// MODE 0: bf16 store row-major (stride N)
// MODE 1: col<2048 -> softplus(acc+bias[col]) bf16 into Cv (stride 2048);
//         2048..2063 -> Bmo fp32 [row][16]; 2064..2079 -> Cmo; >=2080 discard
// MODE 2: acc+resid -> dtype-flagged store (stride N)
template <int MODE, int BM>
__global__ __launch_bounds__(2 * BM) void gemm_bt(
    const short* __restrict__ A, int lda, const short* __restrict__ B,
    void* __restrict__ Cv, int N, int K, const void* __restrict__ aux,
    float* __restrict__ Bmo, float* __restrict__ Cmo,
    const int* __restrict__ flag) {
  __shared__ __align__(16) short As0[BM * 32];
  __shared__ __align__(16) short As1[BM * 32];
  __shared__ __align__(16) short Bs0[128 * 32];
  __shared__ __align__(16) short Bs1[128 * 32];
  const int f32 = *flag;
  const int tid = threadIdx.x;
  const int bm = blockIdx.y * BM;
  const int bn = blockIdx.x << 7;
  const int wid = tid >> 6;
  const int lane = tid & 63;
  const int wm = (wid >> 1) << 6;
  const int wn = (wid & 1) << 6;

  float4v acc[4][4];
  #pragma unroll
  for (int i = 0; i < 4; ++i)
    #pragma unroll
    for (int j = 0; j < 4; ++j) acc[i][j] = (float4v){0.f, 0.f, 0.f, 0.f};

  const int srow = tid >> 2;            // 0 .. BM/2-1
  const int scol = (tid & 3) << 3;
  const short* ga = A + (size_t)(bm + srow) * lda + scol;
  const short* gb = B + (size_t)(bn + srow) * K + scol;   // srow < 128 needed for BM=256 single-DMA B
  const size_t astep = (size_t)(BM / 2) * lda;
  const size_t bstep = (size_t)64 * K;

  const int fr = lane & 15;
  const int fq = (lane >> 4) << 3;

  constexpr int STAGE_DMAS = (BM == 256) ? 3 : 4;
  constexpr int VM_WAIT = 0x3FF0 | STAGE_DMAS;

#define STAGE(Ad, Bd, kk) do {                              \
    async16(&Ad[tid * 8], ga + (kk));                       \
    async16(&Ad[BM * 16 + tid * 8], ga + astep + (kk));     \
    if (BM == 256) {                                        \
      async16(&Bd[tid * 8], gb + (kk));                     \
    } else {                                                \
      async16(&Bd[tid * 8], gb + (kk));                     \
      async16(&Bd[2048 + tid * 8], gb + bstep + (kk));      \
    } } while (0)

  auto compute = [&](const short* Asrc, const short* Bsrc) {
    short8v af[4], bfv[4];
    #pragma unroll
    for (int i = 0; i < 4; ++i)
      af[i] = *(const short8v*)&Asrc[(wm + i * 16 + fr) * 32 + fq];
    #pragma unroll
    for (int j = 0; j < 4; ++j)
      bfv[j] = *(const short8v*)&Bsrc[(wn + j * 16 + fr) * 32 + fq];
    #pragma unroll
    for (int i = 0; i < 4; ++i)
      #pragma unroll
      for (int j = 0; j < 4; ++j)
        acc[i][j] = __builtin_amdgcn_mfma_f32_16x16x32_bf16(af[i], bfv[j], acc[i][j], 0, 0, 0);
  };

  const int nk = K >> 5;   // even for all our K
  STAGE(As0, Bs0, 0);
  for (int k2 = 0; k2 < nk; k2 += 2) {
    STAGE(As1, Bs1, (k2 + 1) << 5);
    __builtin_amdgcn_s_waitcnt(VM_WAIT);
    __builtin_amdgcn_s_barrier();
    compute(As0, Bs0);
    __builtin_amdgcn_s_barrier();
    if (k2 + 2 < nk) {
      STAGE(As0, Bs0, (k2 + 2) << 5);
      __builtin_amdgcn_s_waitcnt(VM_WAIT);
    } else {
      __builtin_amdgcn_s_waitcnt(0x3FF0); // vmcnt(0)
    }
    __builtin_amdgcn_s_barrier();
    compute(As1, Bs1);
    __builtin_amdgcn_s_barrier();
  }
#undef STAGE

  const int er = (lane >> 4) << 2;
  const int ec = lane & 15;
  #pragma unroll
  for (int i = 0; i < 4; ++i) {
    #pragma unroll
    for (int j = 0; j < 4; ++j) {
      const int gcol = bn + wn + j * 16 + ec;
      #pragma unroll
      for (int r = 0; r < 4; ++r) {
        const int grow = bm + wm + i * 16 + er + r;
        float v = acc[i][j][r];
        if (MODE == 1) {
          if (gcol < 2048) {
            v += lde(aux, gcol, f32);
            v = (v > 15.f) ? v : log1pf(__expf(v));
            ((short*)Cv)[(size_t)grow * 2048 + gcol] = f2bf(v);
          } else if (gcol < 2064) {
            Bmo[(size_t)grow * 16 + (gcol - 2048)] = v;
          } else if (gcol < 2080) {
            Cmo[(size_t)grow * 16 + (gcol - 2064)] = v;
          }
        } else {
          const size_t idx = (size_t)grow * N + gcol;
          if (MODE == 2) {
            v += lde(aux, idx, f32);
            if (f32) ((float*)Cv)[idx] = v;
            else     ((short*)Cv)[idx] = f2bf(v);
          } else {
            ((short*)Cv)[idx] = f2bf(v);
          }
        }
      }
    }
  }
}

// -------- causal depthwise conv (K=4) + SiLU ----------
__global__ __launch_bounds__(256) void conv_silu(
    const short* __restrict__ xz, const void* __restrict__ cw,
    const void* __restrict__ cb, short* __restrict__ xc,
    const int* __restrict__ flag) {
  const int f32 = *flag;
  const int row = blockIdx.x;
  const int c0 = threadIdx.x << 3;
  const int t = row & (SEQ - 1);
  float wreg[32], acc[8];
  #pragma unroll
  for (int j = 0; j < 8; ++j) {
    acc[j] = lde(cb, c0 + j, f32);
    #pragma unroll
    for (int k = 0; k < 4; ++k) wreg[j * 4 + k] = lde(cw, (size_t)(c0 + j) * 4 + k, f32);
  }
  #pragma unroll
  for (int k = 0; k < 4; ++k) {
    if (t + k - 3 >= 0) {
      const short8v xv = *(const short8v*)&xz[(size_t)(row + k - 3) * 4096 + c0];
      #pragma unroll
      for (int j = 0; j < 8; ++j) acc[j] += bf2f(xv[j]) * wreg[j * 4 + k];
    }
  }
  short8v ov;
  #pragma unroll
  for (int j = 0; j < 8; ++j) {
    const float a = acc[j];
    ov[j] = f2bf(a / (1.f + __expf(-a)));
  }
  *(short8v*)&xc[(size_t)row * D_INNER + c0] = ov;
}

// -------- chunk-parallel scan, per-thread 16-state, all row-major --------
#define SCAN_CK 64
#define SCAN_ST 32
__global__ __launch_bounds__(1024, 4) void scan_kernel(
    const short* __restrict__ dtb, const short* __restrict__ xcv,
    const float* __restrict__ Bm, const float* __restrict__ Cm,
    short* __restrict__ xzb, const void* __restrict__ A_log,
    const void* __restrict__ Dv, const int* __restrict__ flag) {
  const int f32 = *flag;
  const int tid = threadIdx.x;
  const int dl = tid & 15;
  const int ck = tid >> 4;
  const int di = (blockIdx.x << 4) + dl;
  const int b = blockIdx.y;
  const int r0 = (b << 11) + ck * SCAN_ST;       // global row (b,t0)

  const short* dtp = dtb + (size_t)r0 * 2048 + di;
  const short* xcp = xcv + (size_t)r0 * 2048 + di;
  const float* bmp = Bm + (size_t)r0 * 16;
  const float* cmp = Cm + (size_t)r0 * 16;
  const short* zp = xzb + (size_t)r0 * 4096 + 2048 + di;
  short* yp = xzb + (size_t)r0 * 4096 + di;

  float Ac[16];
  #pragma unroll
  for (int s = 0; s < 16; ++s)
    Ac[s] = -__expf(lde(A_log, (size_t)di * 16 + s, f32));
  const float Dval = lde(Dv, di, f32);

  float h[16];
  #pragma unroll
  for (int s = 0; s < 16; ++s) h[s] = 0.f;
  float sdt = 0.f;

  // pass 1: local scan (h0=0), track sum(dt)
  #pragma unroll 2
  for (int t = 0; t < SCAN_ST; ++t) {
    const float dt = bf2f(dtp[(size_t)t * 2048]);
    const float xc = bf2f(xcp[(size_t)t * 2048]);
    const float4v b0 = *(const float4v*)&bmp[t * 16];
    const float4v b1 = *(const float4v*)&bmp[t * 16 + 4];
    const float4v b2 = *(const float4v*)&bmp[t * 16 + 8];
    const float4v b3 = *(const float4v*)&bmp[t * 16 + 12];
    sdt += dt;
    const float u = xc * dt;
    #pragma unroll
    for (int s = 0; s < 16; ++s) {
      const float bv = (s < 4) ? b0[s] : (s < 8) ? b1[s - 4] : (s < 12) ? b2[s - 8] : b3[s - 12];
      h[s] = h[s] * __expf(Ac[s] * dt) + u * bv;
    }
  }

  __shared__ float sdt_s[SCAN_CK][16];
  __shared__ float hc_s[SCAN_CK][16][17];    // hend in, hstart out (in-place)
  sdt_s[ck][dl] = sdt;
  #pragma unroll
  for (int s = 0; s < 16; ++s) hc_s[ck][dl][s] = h[s];
  __syncthreads();
  if (tid < 256) {
    const int s = tid >> 4;
    const float Acs = -__expf(lde(A_log, (size_t)di * 16 + s, f32));
    float hs = 0.f;
    #pragma unroll 4
    for (int c = 0; c < SCAN_CK; ++c) {
      const float hend = hc_s[c][dl][s];
      hc_s[c][dl][s] = hs;                   // hstart for chunk c
      hs = __expf(Acs * sdt_s[c][dl]) * hs + hend;
    }
  }
  __syncthreads();
  #pragma unroll
  for (int s = 0; s < 16; ++s) h[s] = hc_s[ck][dl][s];

  // pass 2: rescan with true h_start, emit y (coalesced across dl)
  #pragma unroll 2
  for (int t = 0; t < SCAN_ST; ++t) {
    const float dt = bf2f(dtp[(size_t)t * 2048]);
    const float xc = bf2f(xcp[(size_t)t * 2048]);
    const float4v b0 = *(const float4v*)&bmp[t * 16];
    const float4v b1 = *(const float4v*)&bmp[t * 16 + 4];
    const float4v b2 = *(const float4v*)&bmp[t * 16 + 8];
    const float4v b3 = *(const float4v*)&bmp[t * 16 + 12];
    const float4v c0 = *(const float4v*)&cmp[t * 16];
    const float4v c1 = *(const float4v*)&cmp[t * 16 + 4];
    const float4v c2 = *(const float4v*)&cmp[t * 16 + 8];
    const float4v c3 = *(const float4v*)&cmp[t * 16 + 12];
    const float u = xc * dt;
    float p0 = 0.f, p1 = 0.f, p2 = 0.f, p3 = 0.f;
    #pragma unroll
    for (int s = 0; s < 4; ++s) {
      h[s]      = h[s]      * __expf(Ac[s]      * dt) + u * b0[s];
      h[s + 4]  = h[s + 4]  * __expf(Ac[s + 4]  * dt) + u * b1[s];
      h[s + 8]  = h[s + 8]  * __expf(Ac[s + 8]  * dt) + u * b2[s];
      h[s + 12] = h[s + 12] * __expf(Ac[s + 12] * dt) + u * b3[s];
      p0 += h[s] * c0[s];
      p1 += h[s + 4] * c1[s];
      p2 += h[s + 8] * c2[s];
      p3 += h[s + 12] * c3[s];
    }
    const float p = (p0 + p1) + (p2 + p3);
    const float z = bf2f(zp[(size_t)t * 4096]);
    const float sz = z / (1.f + __expf(-z));
    yp[(size_t)t * 4096] = f2bf((p + xc * Dval) * sz);
  }
}

// -------- launch ----------
extern "C" void kernel_launch(void* const* d_in, const int* in_sizes, int n_in,
                              void* d_out, int out_size, void* d_ws, size_t ws_size,
                              hipStream_t stream) {
  const void* x      = d_in[0];
  const void* norm_w = d_in[1];
  const void* norm_b = d_in[2];
  const void* W_in   = d_in[3];
  const void* conv_w = d_in[4];
  const void* conv_b = d_in[5];
  const void* W_dt   = d_in[6];
  const void* b_dt   = d_in[7];
  const void* W_B    = d_in[8];
  const void* W_C    = d_in[9];
  const void* Dv     = d_in[10];
  const void* A_log  = d_in[11];
  const void* W_out  = d_in[12];

  char* ws = (char*)d_ws;
  const size_t MB = (size_t)1 << 20;
  short* wcvt = (short*)(ws);                 //  0-20.5 MB: W_in | [W_dt;W_B;W_C;pad] | W_out
  short* wbuf = wcvt;
  short* wcat = wcvt + WIN_N;                 // 2176 x 2048 bf16
  short* wout = wcvt + WIN_N + WCAT_N;
  int*   flag = (int*)(ws + 21 * MB - 256);
  short* xzb  = (short*)(ws + 21 * MB);       // 21-53 MB [4096 x 4096] (z kept; y overwrites x_part)
  short* xcv  = (short*)(ws + 53 * MB);       // 53-69 MB xc row-major
  short* xn   = (short*)(ws + 69 * MB);       //  8 MB (aliased with dtb)
  short* dtb  = (short*)(ws + 69 * MB);       // 69-85 MB dt row-major [(b,t)][di]
  float* Bm   = (float*)(ws + 85 * MB);       // 256 KB [(b,t)][s]
  float* Cm   = Bm + (size_t)NROWS * 16;      // 256 KB

  probe_kernel<<<1, 64, 0, stream>>>((const unsigned int*)x, flag);
  cvt_kernel<<<5248, 256, 0, stream>>>(W_in, W_dt, W_B, W_C, W_out, wcvt, flag);
  ln_kernel<<<NROWS, 256, 0, stream>>>(x, norm_w, norm_b, xn, flag);
  gemm_bt<0, 256><<<dim3(32, 16), 512, 0, stream>>>(xn, 1024, wbuf, xzb, 4096, 1024, nullptr, nullptr, nullptr, flag);
  conv_silu<<<NROWS, 256, 0, stream>>>(xzb, conv_w, conv_b, xcv, flag);
  gemm_bt<1, 256><<<dim3(17, 16), 512, 0, stream>>>(xcv, 2048, wcat, dtb, 2176, 2048, b_dt, Bm, Cm, flag);
  scan_kernel<<<dim3(128, 2), 1024, 0, stream>>>(dtb, xcv, Bm, Cm, xzb, A_log, Dv, flag);
  gemm_bt<2, 128><<<dim3(8, 32), 256, 0, stream>>>(xzb, 4096, wout, d_out, 1024, 2048, x, nullptr, nullptr, flag);
}